// Round 9
// baseline (973.186 us; speedup 1.0000x reference)
//
#include <hip/hip_runtime.h>
#include <hip/hip_fp16.h>

#define NN 20000      // nodes
#define NE 320000     // edges
#define FE 32         // edge feature dim
#define NG 64         // graphs
#define EA_STRIDE 36  // padded LDS row stride (floats)
#define MAXDEG 64     // fixed-stride in-edge slots; P(Poisson(16) > 64) ~ 1e-22
#define NBLK 1024     // grid: EXACTLY 4 blocks/CU x 256 CU -> all co-resident
#define NTHR 256
#define NWAVE (NBLK * (NTHR / 64))   // 4096 waves
#define NTILE (NE / 16)              // 20000 MFMA tiles

static_assert(NN % 4 == 0, "gat block-reduce assumes node quads");
static_assert((NN % NWAVE) % 4 == 0, "gat per-block-uniform trip counts");
static_assert(NE % 16 == 0, "whole 16-edge tiles");

using f16x8 = __attribute__((ext_vector_type(8))) _Float16;
using f32x4 = __attribute__((ext_vector_type(4))) float;

union AFrag {
    f16x8 v;
    __half2 h2[4];
};

struct Params {
    const float* x; const int* ei; const float* ea; const int* batch;
    const float* We; const float* be; const float* Wroot; const float* bconv;
    const float* Wgat; const float* a_src; const float* a_dst; const float* bgat;
    const float* Wfc1; const float* bfc1; const float* Wfc2; const float* bfc2;
    float* out;
    int* bar; int* deg; float* agg; float* pooled; int* esrc;
    __half* hpb; float* sc_s; float* sc_d; __half* we2t;
};

static __device__ inline int lbound(const int* b, int key) {
    int lo = 0, hi = NN;
    while (lo < hi) { int mid = (lo + hi) >> 1; if (b[mid] < key) lo = mid + 1; else hi = mid; }
    return lo;
}

// Device-scope ticket barrier. All NBLK blocks are guaranteed co-resident
// (grid == residency capacity, enforced by __launch_bounds__(256,4): <=128
// VGPR -> 16 waves/CU -> 4 blocks/CU x 256 CU = 1024). __threadfence is a
// device-scope fence (L1 inv / L2 wb on gfx950) making prior phase's plain
// stores visible across XCDs; atomics are device-scope by default (G12/G16).
static __device__ __forceinline__ void gbar(int* cnt) {
    __threadfence();
    __syncthreads();
    if (threadIdx.x == 0) {
        int t = atomicAdd(cnt, 1);
        int target = (t / NBLK + 1) * NBLK;
        while (atomicAdd(cnt, 0) < target) __builtin_amdgcn_s_sleep(4);
    }
    __syncthreads();
    __threadfence();
}

// ---------------- THE kernel: prep | msg | node | gat | head, barrier-phased ----------
__global__ __launch_bounds__(NTHR, 4) void k_all(Params p) {
    __shared__ float lds[4][2][16 * EA_STRIDE];   // msg: per-wave ea double-buffer
    __shared__ float red[4][64];                  // gat: block pooled-reduce
    __shared__ int sgid[4];

    const int tid  = blockIdx.x * NTHR + threadIdx.x;
    const int lane = threadIdx.x & 63;
    const int wid  = threadIdx.x >> 6;
    const int gw   = tid >> 6;                    // global wave id, < NWAVE

    // ================= P0: zero workspace + build we2t =================
    {
        float4 z4 = {0.f, 0.f, 0.f, 0.f};
        float4* aggv = (float4*)p.agg;
        for (int i = tid; i < NN * 4; i += NBLK * NTHR) aggv[i] = z4;   // agg
        for (int i = tid; i < NN; i += NBLK * NTHR) p.deg[i] = 0;       // deg
        for (int i = tid; i < NG * 64; i += NBLK * NTHR) p.pooled[i] = 0.f;
        // we2t K permutation: k<512: ks=k>>5, r=k&31, q=r>>3, j=r&7;
        // f=16*(q>>1)+ks; i=(q&1)*8+j. k in [512,528): bias row; else zero.
        for (int e2 = tid; e2 < 16 * 544; e2 += NBLK * NTHR) {
            int k = e2 % 544, mm = e2 / 544;
            float v;
            if (k < 512) {
                int ks = k >> 5, r = k & 31, q = r >> 3, j = r & 7;
                int f = 16 * (q >> 1) + ks;
                int i = (q & 1) * 8 + j;
                v = p.We[f * 256 + i * 16 + mm];
            } else if (k < 528) v = p.be[(k - 512) * 16 + mm];
            else v = 0.f;
            p.we2t[e2] = __float2half(v);
        }
    }
    gbar(p.bar);

    // ================= P1: prep (esrc/deg) + msg (MFMA -> atomic agg) ==========
    {   // prep: fixed-stride in-edge lists, slot = atomicAdd(deg[d])
        for (int e = tid; e < NE; e += NBLK * NTHR) {
            int d = p.ei[NE + e];
            int r = atomicAdd(&p.deg[d], 1);
            if (r < MAXDEG) p.esrc[(d << 6) + r] = p.ei[e];
        }
    }
    {   // msg: round-8 pipeline body, grid-stride tiles (bfr amortized ~5 tiles)
        const int m    = lane & 15;
        const int quad = lane >> 4;
        const int pp   = quad >> 1;
        const int xh   = (quad & 1) * 8;
        const int eL   = lane >> 3;
        const int fL   = (lane & 7) * 4;

        const __half* wt = p.we2t + m * 544 + quad * 8;
        f16x8 bfr[17];
        #pragma unroll
        for (int ks = 0; ks < 17; ++ks)
            bfr[ks] = *(const f16x8*)(wt + ks * 32);

        int t = gw;                               // NWAVE < NTILE: always valid
        int e0 = t * 16;
        int r  = e0 + quad * 4 + (m & 3);
        int s  = p.ei[e0 + m];
        int d  = p.ei[NE + r];
        {
            const float4* s0 = (const float4*)(p.ea + (long)t * 512 + lane * 4);
            float4 v0 = s0[0], v1 = s0[64];
            *(float4*)&lds[wid][0][eL * EA_STRIDE + fL]       = v0;
            *(float4*)&lds[wid][0][(8 + eL) * EA_STRIDE + fL] = v1;
        }
        float xf[8];
        {
            const float4* xr = (const float4*)(p.x + s * 16 + xh);
            float4 a0 = xr[0], a1 = xr[1];
            xf[0]=a0.x; xf[1]=a0.y; xf[2]=a0.z; xf[3]=a0.w;
            xf[4]=a1.x; xf[5]=a1.y; xf[6]=a1.z; xf[7]=a1.w;
        }

        int buf = 0;
        while (true) {
            int tn = t + NWAVE;
            bool hasnext = tn < NTILE;            // wave-uniform

            float4 nv0, nv1;
            int s_n = 0, d_n = 0;
            if (hasnext) {
                const float4* sn = (const float4*)(p.ea + (long)tn * 512 + lane * 4);
                nv0 = sn[0]; nv1 = sn[64];
                int e0n = tn * 16;
                int rn  = e0n + quad * 4 + (m & 3);
                s_n = p.ei[e0n + m];
                d_n = p.ei[NE + rn];
            }

            float4 ev[4];
            #pragma unroll
            for (int q = 0; q < 4; ++q)
                ev[q] = *(const float4*)&lds[wid][buf][m * EA_STRIDE + pp * 16 + q * 4];

            __half2 xp[4];
            #pragma unroll
            for (int j = 0; j < 4; ++j)
                xp[j] = __float22half2_rn(make_float2(xf[2*j], xf[2*j+1]));

            f32x4 acc = {0.f, 0.f, 0.f, 0.f};
            #pragma unroll
            for (int ks = 0; ks < 16; ++ks) {
                float evv = ((const float*)ev)[ks];
                __half2 eh = __float2half2_rn(evv);
                AFrag a;
                #pragma unroll
                for (int j = 0; j < 4; ++j) a.h2[j] = __hmul2(eh, xp[j]);
                acc = __builtin_amdgcn_mfma_f32_16x16x32_f16(a.v, bfr[ks], acc, 0, 0, 0);
            }
            {
                AFrag a;
                #pragma unroll
                for (int j = 0; j < 4; ++j) a.h2[j] = xp[j];
                acc = __builtin_amdgcn_mfma_f32_16x16x32_f16(a.v, bfr[16], acc, 0, 0, 0);
            }

            if (hasnext) {
                const float4* xr = (const float4*)(p.x + s_n * 16 + xh);
                float4 a0 = xr[0], a1 = xr[1];
                xf[0]=a0.x; xf[1]=a0.y; xf[2]=a0.z; xf[3]=a0.w;
                xf[4]=a1.x; xf[5]=a1.y; xf[6]=a1.z; xf[7]=a1.w;
            }

            // C row = quad*4+rr (edge), col = m (feature); lane (quad<<4)|rr holds dst
            #pragma unroll
            for (int rr = 0; rr < 4; ++rr) {
                int dd = __shfl(d, (quad << 4) | rr);
                atomicAdd(&p.agg[dd * 16 + m], acc[rr]);
            }

            if (!hasnext) break;
            buf ^= 1;
            *(float4*)&lds[wid][buf][eL * EA_STRIDE + fL]       = nv0;
            *(float4*)&lds[wid][buf][(8 + eL) * EA_STRIDE + fL] = nv1;
            s = s_n; d = d_n; t = tn;
        }
    }
    gbar(p.bar);

    // ================= P2: node — h, hp, scores =================
    for (int n = gw; n < NN; n += NWAVE) {        // wave-uniform loop
        int o = lane & 15;
        float agv = p.agg[n * 16 + o];
        float xv = p.x[n * 16 + o];
        float acc = p.bconv[o] + agv;
        #pragma unroll
        for (int i = 0; i < 16; ++i) acc += __shfl(xv, i) * p.Wroot[i * 16 + o];
        float hv = fmaxf(acc, 0.f);
        float hpacc = 0.f;
        #pragma unroll
        for (int i = 0; i < 16; ++i) hpacc += __shfl(hv, i) * p.Wgat[i * 64 + lane];
        p.hpb[(long)n * 64 + lane] = __float2half(hpacc);
        float ss = hpacc * p.a_src[lane];
        float sd = hpacc * p.a_dst[lane];
        #pragma unroll
        for (int off = 32; off; off >>= 1) {
            ss += __shfl_xor(ss, off);
            sd += __shfl_xor(sd, off);
        }
        if (lane == 0) { p.sc_s[n] = ss; p.sc_d[n] = sd; }
    }
    gbar(p.bar);

    // ================= P3: gat + block-reduced mean-pool =================
    // NN % NWAVE = 3616 == 0 mod 4 -> 'act' is block-uniform every iteration,
    // so the in-loop __syncthreads is safe.
    for (int n0 = 0; n0 < NN; n0 += NWAVE) {
        int n = n0 + gw;
        bool act = n < NN;
        float g = 0.f;
        int gid = -1 - wid;                       // unique sentinel if inactive
        if (act) {
            float sdv = p.sc_d[n];
            gid = p.batch[n];
            float es = p.sc_s[n] + sdv;
            es = (es >= 0.f) ? es : 0.2f * es;
            float l0 = __expf(es);
            float acc = l0 * __half2float(p.hpb[(long)n * 64 + lane]);

            int cnt = p.deg[n]; if (cnt > MAXDEG) cnt = MAXDEG;   // wave-uniform
            bool valid = lane < cnt;
            int s = valid ? p.esrc[(n << 6) + lane] : 0;
            float sc = valid ? p.sc_s[s] + sdv : 0.f;
            sc = (sc >= 0.f) ? sc : 0.2f * sc;
            float pj = valid ? __expf(sc) : 0.f;
            float lsum = pj;

            int k2 = 0;
            for (; k2 + 8 <= cnt; k2 += 8) {      // 8 hpb loads in flight
                int   e0 = __shfl(s, k2),     e1 = __shfl(s, k2 + 1);
                int   e2 = __shfl(s, k2 + 2), e3 = __shfl(s, k2 + 3);
                int   e4 = __shfl(s, k2 + 4), e5 = __shfl(s, k2 + 5);
                int   e6 = __shfl(s, k2 + 6), e7 = __shfl(s, k2 + 7);
                float q0 = __shfl(pj, k2),     q1 = __shfl(pj, k2 + 1);
                float q2 = __shfl(pj, k2 + 2), q3 = __shfl(pj, k2 + 3);
                float q4 = __shfl(pj, k2 + 4), q5 = __shfl(pj, k2 + 5);
                float q6 = __shfl(pj, k2 + 6), q7 = __shfl(pj, k2 + 7);
                float h0 = __half2float(p.hpb[(long)e0 * 64 + lane]);
                float h1 = __half2float(p.hpb[(long)e1 * 64 + lane]);
                float h2 = __half2float(p.hpb[(long)e2 * 64 + lane]);
                float h3 = __half2float(p.hpb[(long)e3 * 64 + lane]);
                float h4 = __half2float(p.hpb[(long)e4 * 64 + lane]);
                float h5 = __half2float(p.hpb[(long)e5 * 64 + lane]);
                float h6 = __half2float(p.hpb[(long)e6 * 64 + lane]);
                float h7 = __half2float(p.hpb[(long)e7 * 64 + lane]);
                acc += q0 * h0 + q1 * h1 + q2 * h2 + q3 * h3
                     + q4 * h4 + q5 * h5 + q6 * h6 + q7 * h7;
            }
            for (; k2 + 4 <= cnt; k2 += 4) {
                int   e0 = __shfl(s, k2),     e1 = __shfl(s, k2 + 1);
                int   e2 = __shfl(s, k2 + 2), e3 = __shfl(s, k2 + 3);
                float q0 = __shfl(pj, k2),     q1 = __shfl(pj, k2 + 1);
                float q2 = __shfl(pj, k2 + 2), q3 = __shfl(pj, k2 + 3);
                float h0 = __half2float(p.hpb[(long)e0 * 64 + lane]);
                float h1 = __half2float(p.hpb[(long)e1 * 64 + lane]);
                float h2 = __half2float(p.hpb[(long)e2 * 64 + lane]);
                float h3 = __half2float(p.hpb[(long)e3 * 64 + lane]);
                acc += q0 * h0 + q1 * h1 + q2 * h2 + q3 * h3;
            }
            for (; k2 < cnt; ++k2) {
                int sk = __shfl(s, k2);
                float pk = __shfl(pj, k2);
                acc += pk * __half2float(p.hpb[(long)sk * 64 + lane]);
            }
            #pragma unroll
            for (int off = 32; off; off >>= 1) lsum += __shfl_xor(lsum, off);
            g = acc / (lsum + l0) + p.bgat[lane];
            g = fmaxf(g, 0.f);
        }

        // block reduce: batch sorted -> block's waves usually share gid
        red[wid][lane] = g;
        if (lane == 0) sgid[wid] = gid;
        __syncthreads();
        int mygid = sgid[wid];
        bool leader = act;
        #pragma unroll
        for (int w2 = 0; w2 < 3; ++w2)
            if (w2 < wid && sgid[w2] == mygid) leader = false;
        if (leader) {
            float tot = g;
            #pragma unroll
            for (int w2 = 1; w2 < 4; ++w2)
                if (w2 > wid && sgid[w2] == mygid) tot += red[w2][lane];
            atomicAdd(&p.pooled[mygid * 64 + lane], tot);
        }
        __syncthreads();                          // red/sgid reused next iter
    }
    gbar(p.bar);

    // ================= P4: head — one wave per graph =================
    if (gw < NG) {
        int g = gw;
        int r0 = lbound(p.batch, g);
        int r1 = lbound(p.batch, g + 1);
        float inv = 1.f / (float)((r1 - r0) > 0 ? (r1 - r0) : 1);
        float plv = p.pooled[g * 64 + lane] * inv;
        float a0 = p.bfc1[lane], a1 = p.bfc1[64 + lane];
        #pragma unroll 8
        for (int i = 0; i < 64; ++i) {
            float pi = __shfl(plv, i);
            a0 += pi * p.Wfc1[i * 128 + lane];
            a1 += pi * p.Wfc1[i * 128 + 64 + lane];
        }
        a0 = fmaxf(a0, 0.f);
        a1 = fmaxf(a1, 0.f);
        float v = a0 * p.Wfc2[lane] + a1 * p.Wfc2[64 + lane];
        #pragma unroll
        for (int off = 32; off; off >>= 1) v += __shfl_xor(v, off);
        if (lane == 0) p.out[g] = v + p.bfc2[0];
    }
}

extern "C" void kernel_launch(void* const* d_in, const int* in_sizes, int n_in,
                              void* d_out, int out_size, void* d_ws, size_t ws_size,
                              hipStream_t stream) {
    (void)in_sizes; (void)n_in; (void)out_size; (void)ws_size;
    char* w = (char*)d_ws;
    size_t o_bar = 0;                               // bar     64 B (memset-zeroed)
    size_t o_deg = 64;                              // deg     NN int      (P0-zeroed)
    size_t o_agg = o_deg + (size_t)NN * 4;          // agg     NN*16 f32   (P0-zeroed)
    size_t o_pl  = o_agg + (size_t)NN * 16 * 4;     // pooled  NG*64 f32   (P0-zeroed)
    size_t o_es  = o_pl  + (size_t)NG * 64 * 4;
    o_es = (o_es + 63) & ~(size_t)63;               // esrc    NN*64 int (5.12MB)
    size_t o_hp  = o_es + (size_t)NN * 64 * 4;      // hpb     NN*64 f16
    size_t o_ss  = o_hp + (size_t)NN * 64 * 2;      // sc_s    NN f32
    size_t o_sd  = o_ss + (size_t)NN * 4;           // sc_d    NN f32
    size_t o_wt  = o_sd + (size_t)NN * 4;           // we2t    16*544 f16
    o_wt = (o_wt + 15) & ~(size_t)15;

    Params P;
    P.x     = (const float*)d_in[0];
    P.ei    = (const int*)d_in[1];
    P.ea    = (const float*)d_in[2];
    P.batch = (const int*)d_in[3];
    P.We    = (const float*)d_in[4];
    P.be    = (const float*)d_in[5];
    P.Wroot = (const float*)d_in[6];
    P.bconv = (const float*)d_in[7];
    P.Wgat  = (const float*)d_in[8];
    P.a_src = (const float*)d_in[9];
    P.a_dst = (const float*)d_in[10];
    P.bgat  = (const float*)d_in[11];
    P.Wfc1  = (const float*)d_in[12];
    P.bfc1  = (const float*)d_in[13];
    P.Wfc2  = (const float*)d_in[14];
    P.bfc2  = (const float*)d_in[15];
    P.out   = (float*)d_out;
    P.bar    = (int*)(w + o_bar);
    P.deg    = (int*)(w + o_deg);
    P.agg    = (float*)(w + o_agg);
    P.pooled = (float*)(w + o_pl);
    P.esrc   = (int*)(w + o_es);
    P.hpb    = (__half*)(w + o_hp);
    P.sc_s   = (float*)(w + o_ss);
    P.sc_d   = (float*)(w + o_sd);
    P.we2t   = (__half*)(w + o_wt);

    (void)hipMemsetAsync(w, 0, 64, stream);   // barrier counter only
    k_all<<<NBLK, NTHR, 0, stream>>>(P);
}

// Round 11
// 314.560 us; speedup vs baseline: 3.0938x; 3.0938x over previous
//
#include <hip/hip_runtime.h>
#include <hip/hip_fp16.h>

#define NN 20000      // nodes
#define NE 320000     // edges
#define FE 32         // edge feature dim
#define NG 64         // graphs
#define EA_STRIDE 36  // padded LDS row stride (floats)
#define MAXDEG 64     // fixed-stride in-edge slots; P(Poisson(16) > 64) ~ 1e-22
#define GATBLK (NN / 4)   // k_gathead grid

static_assert(NN % 4 == 0, "k_gathead assumes full blocks of 4 nodes");
static_assert(NE % 32 == 0, "k_msgprep assumes whole 16-edge tiles, TPW=2");
static_assert(NN * 16 % 4 == 0, "agg zeroed as float4");

using f16x8 = __attribute__((ext_vector_type(8))) _Float16;
using f32x4 = __attribute__((ext_vector_type(4))) float;

union AFrag {
    f16x8 v;
    __half2 h2[4];
};

struct Params {
    const float* x; const int* ei; const float* ea; const int* batch;
    const float* We; const float* be; const float* Wroot; const float* bconv;
    const float* Wgat; const float* a_src; const float* a_dst; const float* bgat;
    const float* Wfc1; const float* bfc1; const float* Wfc2; const float* bfc2;
    float* out;
    int* done; int* deg; float* agg; float* pooled; int* esrc;
    __half* hpb; float* sc_s; float* sc_d; __half* we2t;
};

static __device__ inline int lbound(const int* b, int key) {
    int lo = 0, hi = NN;
    while (lo < hi) { int mid = (lo + hi) >> 1; if (b[mid] < key) lo = mid + 1; else hi = mid; }
    return lo;
}

static __device__ inline float atomic_load_f(const float* ptr) {
    // agent(device)-scope atomic load: coherent with other blocks' atomicAdds
    return __hip_atomic_load(ptr, __ATOMIC_RELAXED, __HIP_MEMORY_SCOPE_AGENT);
}

// ---------------- K0: init — zero deg/agg/pooled/done + build we2t ----------------
// Replaces hipMemsetAsync AND unblocks prep+msg fusion (we2t no longer built in prep).
// we2t K permutation: k<512: ks=k>>5, r=k&31, q=r>>3, j=r&7; f=16*(q>>1)+ks;
// i=(q&1)*8+j. k in [512,528): bias row i=k-512; else zero.
__global__ __launch_bounds__(256) void k_init(Params p) {
    int t = blockIdx.x * blockDim.x + threadIdx.x;   // 320 x 256 = 81920 threads
    float4 z4 = {0.f, 0.f, 0.f, 0.f};
    if (t < NN * 4) ((float4*)p.agg)[t] = z4;        // agg: NN*16 f32 = NN*4 float4
    if (t < NN) p.deg[t] = 0;
    if (t < NG * 64) p.pooled[t] = 0.f;
    if (t == 0) *p.done = 0;
    if (t < 16 * 544) {
        int k = t % 544, m = t / 544;
        float v;
        if (k < 512) {
            int ks = k >> 5, r = k & 31, q = r >> 3, j = r & 7;
            int f = 16 * (q >> 1) + ks;
            int i = (q & 1) * 8 + j;
            v = p.We[f * 256 + i * 16 + m];
        } else if (k < 528) v = p.be[(k - 512) * 16 + m];
        else v = 0.f;
        p.we2t[t] = __float2half(v);
    }
}

// ---------------- K1: prep + msg fused (independent work, one dispatch) ----------
// prep (deg/esrc) feeds only k_gathead (later dispatch); msg needs only we2t
// (built in k_init). The prep atomic chain rides in msg's idle latency slots.
// msg body = round-8's proven TPW=2 LDS pipeline + atomicAdd agg.
#define TPW 2
__global__ __launch_bounds__(256, 2) void k_msgprep(Params p) {
    __shared__ float lds[4][2][16 * EA_STRIDE];
    const int tid  = blockIdx.x * blockDim.x + threadIdx.x;
    const int lane = threadIdx.x & 63;
    const int wid  = threadIdx.x >> 6;
    const int m    = lane & 15;
    const int quad = lane >> 4;
    const int pp   = quad >> 1;
    const int xh   = (quad & 1) * 8;
    const int eL   = lane >> 3;
    const int fL   = (lane & 7) * 4;

    // ---- prep portion: fixed-stride in-edge lists (first NE threads) ----
    if (tid < NE) {
        int dd = p.ei[NE + tid];
        int rr = atomicAdd(&p.deg[dd], 1);
        if (rr < MAXDEG) p.esrc[(dd << 6) + rr] = p.ei[tid];
    }

    // ---- msg portion ----
    const int gw = blockIdx.x * 4 + wid;   // 2500 blocks x 4 waves
    const int t0 = gw * TPW;

    const __half* wt = p.we2t + m * 544 + quad * 8;
    f16x8 bfr[17];
    #pragma unroll
    for (int ks = 0; ks < 17; ++ks)
        bfr[ks] = *(const f16x8*)(wt + ks * 32);

    int e0 = t0 * 16;
    int r  = e0 + quad * 4 + (m & 3);
    int s  = p.ei[e0 + m];
    int d  = p.ei[NE + r];
    {
        const float4* s0 = (const float4*)(p.ea + (long)t0 * 512 + lane * 4);
        float4 v0 = s0[0], v1 = s0[64];
        *(float4*)&lds[wid][0][eL * EA_STRIDE + fL]       = v0;
        *(float4*)&lds[wid][0][(8 + eL) * EA_STRIDE + fL] = v1;
    }
    float xf[8];
    {
        const float4* xr = (const float4*)(p.x + s * 16 + xh);
        float4 a0 = xr[0], a1 = xr[1];
        xf[0]=a0.x; xf[1]=a0.y; xf[2]=a0.z; xf[3]=a0.w;
        xf[4]=a1.x; xf[5]=a1.y; xf[6]=a1.z; xf[7]=a1.w;
    }

    int buf = 0;
    #pragma unroll
    for (int it = 0; it < TPW; ++it) {
        const int tile = t0 + it;
        const bool hasnext = it < TPW - 1;

        float4 nv0, nv1;
        int s_n = 0, d_n = 0;
        if (hasnext) {
            const float4* sn = (const float4*)(p.ea + (long)(tile + 1) * 512 + lane * 4);
            nv0 = sn[0]; nv1 = sn[64];
            int e0n = (tile + 1) * 16;
            int rn  = e0n + quad * 4 + (m & 3);
            s_n = p.ei[e0n + m];
            d_n = p.ei[NE + rn];
        }

        float4 ev[4];
        #pragma unroll
        for (int q = 0; q < 4; ++q)
            ev[q] = *(const float4*)&lds[wid][buf][m * EA_STRIDE + pp * 16 + q * 4];

        __half2 xp[4];
        #pragma unroll
        for (int j = 0; j < 4; ++j)
            xp[j] = __float22half2_rn(make_float2(xf[2*j], xf[2*j+1]));

        f32x4 acc = {0.f, 0.f, 0.f, 0.f};
        #pragma unroll
        for (int ks = 0; ks < 16; ++ks) {
            float evv = ((const float*)ev)[ks];
            __half2 eh = __float2half2_rn(evv);
            AFrag a;
            #pragma unroll
            for (int j = 0; j < 4; ++j) a.h2[j] = __hmul2(eh, xp[j]);
            acc = __builtin_amdgcn_mfma_f32_16x16x32_f16(a.v, bfr[ks], acc, 0, 0, 0);
        }
        {
            AFrag a;
            #pragma unroll
            for (int j = 0; j < 4; ++j) a.h2[j] = xp[j];
            acc = __builtin_amdgcn_mfma_f32_16x16x32_f16(a.v, bfr[16], acc, 0, 0, 0);
        }

        if (hasnext) {
            const float4* xr = (const float4*)(p.x + s_n * 16 + xh);
            float4 a0 = xr[0], a1 = xr[1];
            xf[0]=a0.x; xf[1]=a0.y; xf[2]=a0.z; xf[3]=a0.w;
            xf[4]=a1.x; xf[5]=a1.y; xf[6]=a1.z; xf[7]=a1.w;
        }

        // C row = quad*4+rr (edge), col = m (feature); lane (quad<<4)|rr holds dst
        #pragma unroll
        for (int rr = 0; rr < 4; ++rr) {
            int dd = __shfl(d, (quad << 4) | rr);
            atomicAdd(&p.agg[dd * 16 + m], acc[rr]);
        }

        if (hasnext) {
            buf ^= 1;
            *(float4*)&lds[wid][buf][eL * EA_STRIDE + fL]       = nv0;
            *(float4*)&lds[wid][buf][(8 + eL) * EA_STRIDE + fL] = nv1;
            s = s_n; d = d_n;
        }
    }
}

// ---------------- K2: node — h, hp, scores (direct agg read) ----------------
__global__ __launch_bounds__(256) void k_node(Params p) {
    int n = (blockIdx.x * blockDim.x + threadIdx.x) >> 6;
    int lane = threadIdx.x & 63;
    if (n >= NN) return;
    int o = lane & 15;
    float agv = p.agg[n * 16 + o];
    float xv = p.x[n * 16 + o];
    float acc = p.bconv[o] + agv;
    #pragma unroll
    for (int i = 0; i < 16; ++i) acc += __shfl(xv, i) * p.Wroot[i * 16 + o];
    float hv = fmaxf(acc, 0.f);
    float hpacc = 0.f;
    #pragma unroll
    for (int i = 0; i < 16; ++i) hpacc += __shfl(hv, i) * p.Wgat[i * 64 + lane];
    p.hpb[(long)n * 64 + lane] = __float2half(hpacc);
    float ss = hpacc * p.a_src[lane];
    float sd = hpacc * p.a_dst[lane];
    #pragma unroll
    for (int off = 32; off; off >>= 1) {
        ss += __shfl_xor(ss, off);
        sd += __shfl_xor(sd, off);
    }
    if (lane == 0) { p.sc_s[n] = ss; p.sc_d[n] = sd; }
}

// ---------------- K3: GAT + pool + FUSED head (last-block-done tail) ----------------
__global__ __launch_bounds__(256) void k_gathead(Params p) {
    __shared__ float red[4][64];
    __shared__ int sgid[4];
    __shared__ int lastflag;
    int wid = threadIdx.x >> 6;
    int d = (blockIdx.x * blockDim.x + threadIdx.x) >> 6;   // grid exact: NN/4 blocks
    int lane = threadIdx.x & 63;
    float sdv = p.sc_d[d];
    int gid = p.batch[d];
    float es = p.sc_s[d] + sdv;
    es = (es >= 0.f) ? es : 0.2f * es;
    float l0 = __expf(es);
    float acc = l0 * __half2float(p.hpb[(long)d * 64 + lane]);

    int cnt = p.deg[d]; if (cnt > MAXDEG) cnt = MAXDEG;     // wave-uniform
    bool valid = lane < cnt;
    int s = valid ? p.esrc[(d << 6) + lane] : 0;
    float sc = valid ? p.sc_s[s] + sdv : 0.f;
    sc = (sc >= 0.f) ? sc : 0.2f * sc;
    float pj = valid ? __expf(sc) : 0.f;
    float lsum = pj;

    int k2 = 0;
    for (; k2 + 8 <= cnt; k2 += 8) {       // 8 hpb loads in flight
        int   e0 = __shfl(s, k2),     e1 = __shfl(s, k2 + 1);
        int   e2 = __shfl(s, k2 + 2), e3 = __shfl(s, k2 + 3);
        int   e4 = __shfl(s, k2 + 4), e5 = __shfl(s, k2 + 5);
        int   e6 = __shfl(s, k2 + 6), e7 = __shfl(s, k2 + 7);
        float q0 = __shfl(pj, k2),     q1 = __shfl(pj, k2 + 1);
        float q2 = __shfl(pj, k2 + 2), q3 = __shfl(pj, k2 + 3);
        float q4 = __shfl(pj, k2 + 4), q5 = __shfl(pj, k2 + 5);
        float q6 = __shfl(pj, k2 + 6), q7 = __shfl(pj, k2 + 7);
        float h0 = __half2float(p.hpb[(long)e0 * 64 + lane]);
        float h1 = __half2float(p.hpb[(long)e1 * 64 + lane]);
        float h2 = __half2float(p.hpb[(long)e2 * 64 + lane]);
        float h3 = __half2float(p.hpb[(long)e3 * 64 + lane]);
        float h4 = __half2float(p.hpb[(long)e4 * 64 + lane]);
        float h5 = __half2float(p.hpb[(long)e5 * 64 + lane]);
        float h6 = __half2float(p.hpb[(long)e6 * 64 + lane]);
        float h7 = __half2float(p.hpb[(long)e7 * 64 + lane]);
        acc += q0 * h0 + q1 * h1 + q2 * h2 + q3 * h3
             + q4 * h4 + q5 * h5 + q6 * h6 + q7 * h7;
    }
    for (; k2 + 4 <= cnt; k2 += 4) {
        int   e0 = __shfl(s, k2),     e1 = __shfl(s, k2 + 1);
        int   e2 = __shfl(s, k2 + 2), e3 = __shfl(s, k2 + 3);
        float q0 = __shfl(pj, k2),     q1 = __shfl(pj, k2 + 1);
        float q2 = __shfl(pj, k2 + 2), q3 = __shfl(pj, k2 + 3);
        float h0 = __half2float(p.hpb[(long)e0 * 64 + lane]);
        float h1 = __half2float(p.hpb[(long)e1 * 64 + lane]);
        float h2 = __half2float(p.hpb[(long)e2 * 64 + lane]);
        float h3 = __half2float(p.hpb[(long)e3 * 64 + lane]);
        acc += q0 * h0 + q1 * h1 + q2 * h2 + q3 * h3;
    }
    for (; k2 < cnt; ++k2) {
        int sk = __shfl(s, k2);
        float pk = __shfl(pj, k2);
        acc += pk * __half2float(p.hpb[(long)sk * 64 + lane]);
    }

    #pragma unroll
    for (int off = 32; off; off >>= 1) lsum += __shfl_xor(lsum, off);
    float g = acc / (lsum + l0) + p.bgat[lane];
    g = fmaxf(g, 0.f);

    // block reduce: batch sorted -> block's waves usually share gid
    red[wid][lane] = g;
    if (lane == 0) sgid[wid] = gid;
    __syncthreads();
    bool leader = true;
    #pragma unroll
    for (int w2 = 0; w2 < 3; ++w2)
        if (w2 < wid && sgid[w2] == gid) leader = false;
    if (leader) {
        float tot = g;
        #pragma unroll
        for (int w2 = 1; w2 < 4; ++w2)
            if (w2 > wid && sgid[w2] == gid) tot += red[w2][lane];
        float old = atomicAdd(&p.pooled[gid * 64 + lane], tot);
        // consume the return: forces the RMW ack (performed at coherence point)
        // BEFORE this block's done-increment below.
        asm volatile("" :: "v"(old));
    }
    __syncthreads();

    // ---- last-block-done head: one atomic per block, no polling ----
    if (threadIdx.x == 0) {
        int oldc = atomicAdd(p.done, 1);
        lastflag = (oldc == GATBLK - 1);
    }
    __syncthreads();
    if (lastflag) {
        // Executed by exactly ONE block, once: ~ns cost. Makes pooled-visibility
        // independent of relaxed-load ordering assumptions (defensive, G16).
        __threadfence();
        // 4 waves x 16 graphs each; pooled read with agent-scope atomic loads
        for (int k = 0; k < 16; ++k) {
            int g2 = wid * 16 + k;
            int r0 = lbound(p.batch, g2);
            int r1 = lbound(p.batch, g2 + 1);
            float inv = 1.f / (float)((r1 - r0) > 0 ? (r1 - r0) : 1);
            float plv = atomic_load_f(&p.pooled[g2 * 64 + lane]) * inv;
            float a0 = p.bfc1[lane], a1 = p.bfc1[64 + lane];
            #pragma unroll 8
            for (int i = 0; i < 64; ++i) {
                float pi = __shfl(plv, i);
                a0 += pi * p.Wfc1[i * 128 + lane];
                a1 += pi * p.Wfc1[i * 128 + 64 + lane];
            }
            a0 = fmaxf(a0, 0.f);
            a1 = fmaxf(a1, 0.f);
            float v = a0 * p.Wfc2[lane] + a1 * p.Wfc2[64 + lane];
            #pragma unroll
            for (int off = 32; off; off >>= 1) v += __shfl_xor(v, off);
            if (lane == 0) p.out[g2] = v + p.bfc2[0];
        }
    }
}

extern "C" void kernel_launch(void* const* d_in, const int* in_sizes, int n_in,
                              void* d_out, int out_size, void* d_ws, size_t ws_size,
                              hipStream_t stream) {
    (void)in_sizes; (void)n_in; (void)out_size; (void)ws_size;
    char* w = (char*)d_ws;
    size_t o_dn  = 0;                               // done    64 B (k_init-zeroed)
    size_t o_deg = 64;                              // deg     NN int      (k_init)
    size_t o_agg = o_deg + (size_t)NN * 4;          // agg     NN*16 f32   (k_init)
    size_t o_pl  = o_agg + (size_t)NN * 16 * 4;     // pooled  NG*64 f32   (k_init)
    size_t o_es  = o_pl  + (size_t)NG * 64 * 4;
    o_es = (o_es + 63) & ~(size_t)63;               // esrc    NN*64 int (5.12MB)
    size_t o_hp  = o_es + (size_t)NN * 64 * 4;      // hpb     NN*64 f16
    size_t o_ss  = o_hp + (size_t)NN * 64 * 2;      // sc_s    NN f32
    size_t o_sd  = o_ss + (size_t)NN * 4;           // sc_d    NN f32
    size_t o_wt  = o_sd + (size_t)NN * 4;           // we2t    16*544 f16 (k_init)
    o_wt = (o_wt + 15) & ~(size_t)15;

    Params P;
    P.x     = (const float*)d_in[0];
    P.ei    = (const int*)d_in[1];
    P.ea    = (const float*)d_in[2];
    P.batch = (const int*)d_in[3];
    P.We    = (const float*)d_in[4];
    P.be    = (const float*)d_in[5];
    P.Wroot = (const float*)d_in[6];
    P.bconv = (const float*)d_in[7];
    P.Wgat  = (const float*)d_in[8];
    P.a_src = (const float*)d_in[9];
    P.a_dst = (const float*)d_in[10];
    P.bgat  = (const float*)d_in[11];
    P.Wfc1  = (const float*)d_in[12];
    P.bfc1  = (const float*)d_in[13];
    P.Wfc2  = (const float*)d_in[14];
    P.bfc2  = (const float*)d_in[15];
    P.out   = (float*)d_out;
    P.done   = (int*)(w + o_dn);
    P.deg    = (int*)(w + o_deg);
    P.agg    = (float*)(w + o_agg);
    P.pooled = (float*)(w + o_pl);
    P.esrc   = (int*)(w + o_es);
    P.hpb    = (__half*)(w + o_hp);
    P.sc_s   = (float*)(w + o_ss);
    P.sc_d   = (float*)(w + o_sd);
    P.we2t   = (__half*)(w + o_wt);

    k_init<<<320, 256, 0, stream>>>(P);            // replaces memset + we2t build
    k_msgprep<<<2500, 256, 0, stream>>>(P);        // prep + msg fused
    k_node<<<(NN + 3) / 4, 256, 0, stream>>>(P);
    k_gathead<<<GATBLK, 256, 0, stream>>>(P);      // gat + pool + head fused
}

// Round 12
// 258.953 us; speedup vs baseline: 3.7582x; 1.2147x over previous
//
#include <hip/hip_runtime.h>
#include <hip/hip_fp16.h>

#define NN 20000      // nodes
#define NE 320000     // edges
#define FE 32         // edge feature dim
#define NG 64         // graphs
#define EA_STRIDE 36  // padded LDS row stride (floats)
#define MAXDEG 64     // fixed-stride in-edge slots; P(Poisson(16) > 64) ~ 1e-22
#define GATBLK (NN / 4)             // k_gathead grid = 5000
#define NCHUNK ((GATBLK + 63) / 64) // 79 level-1 done counters

static_assert(NN % 4 == 0, "k_gathead assumes full blocks of 4 nodes");
static_assert(NE % 32 == 0, "k_msgprep assumes whole 16-edge tiles, TPW=2");
static_assert(NN * 16 % 4 == 0, "agg zeroed as float4");

using f16x8 = __attribute__((ext_vector_type(8))) _Float16;
using f32x4 = __attribute__((ext_vector_type(4))) float;

union AFrag {
    f16x8 v;
    __half2 h2[4];
};

struct Params {
    const float* x; const int* ei; const float* ea; const int* batch;
    const float* We; const float* be; const float* Wroot; const float* bconv;
    const float* Wgat; const float* a_src; const float* a_dst; const float* bgat;
    const float* Wfc1; const float* bfc1; const float* Wfc2; const float* bfc2;
    float* out;
    int* done; int* dchunk; int* deg; float* agg; float* pooled; int* esrc;
    __half* hpb; float* sc_s; float* sc_d; __half* we2t;
};

static __device__ inline int lbound(const int* b, int key) {
    int lo = 0, hi = NN;
    while (lo < hi) { int mid = (lo + hi) >> 1; if (b[mid] < key) lo = mid + 1; else hi = mid; }
    return lo;
}

static __device__ inline float atomic_load_f(const float* ptr) {
    // agent(device)-scope atomic load: coherent with other blocks' atomicAdds
    return __hip_atomic_load(ptr, __ATOMIC_RELAXED, __HIP_MEMORY_SCOPE_AGENT);
}

// ---------------- K0: init — zero counters/agg/pooled + build we2t ----------------
// we2t K permutation: k<512: ks=k>>5, r=k&31, q=r>>3, j=r&7; f=16*(q>>1)+ks;
// i=(q&1)*8+j. k in [512,528): bias row i=k-512; else zero.
__global__ __launch_bounds__(256) void k_init(Params p) {
    int t = blockIdx.x * blockDim.x + threadIdx.x;   // 320 x 256 = 81920 threads
    float4 z4 = {0.f, 0.f, 0.f, 0.f};
    if (t < NN * 4) ((float4*)p.agg)[t] = z4;        // agg: NN*16 f32 = NN*4 float4
    if (t < NN) p.deg[t] = 0;
    if (t < NG * 64) p.pooled[t] = 0.f;
    if (t == 0) *p.done = 0;
    if (t < NCHUNK * 16) p.dchunk[t] = 0;            // 79 counters, 64B-strided
    if (t < 16 * 544) {
        int k = t % 544, m = t / 544;
        float v;
        if (k < 512) {
            int ks = k >> 5, r = k & 31, q = r >> 3, j = r & 7;
            int f = 16 * (q >> 1) + ks;
            int i = (q & 1) * 8 + j;
            v = p.We[f * 256 + i * 16 + m];
        } else if (k < 528) v = p.be[(k - 512) * 16 + m];
        else v = 0.f;
        p.we2t[t] = __float2half(v);
    }
}

// ---------------- K1: prep + msg fused (independent work, one dispatch) ----------
// prep (deg/esrc) feeds only k_gathead (later dispatch); msg needs only we2t
// (built in k_init). The prep atomic chain rides in msg's idle latency slots.
// msg body = round-8's proven TPW=2 LDS pipeline + atomicAdd agg.
#define TPW 2
__global__ __launch_bounds__(256, 2) void k_msgprep(Params p) {
    __shared__ float lds[4][2][16 * EA_STRIDE];
    const int tid  = blockIdx.x * blockDim.x + threadIdx.x;
    const int lane = threadIdx.x & 63;
    const int wid  = threadIdx.x >> 6;
    const int m    = lane & 15;
    const int quad = lane >> 4;
    const int pp   = quad >> 1;
    const int xh   = (quad & 1) * 8;
    const int eL   = lane >> 3;
    const int fL   = (lane & 7) * 4;

    // ---- prep portion: fixed-stride in-edge lists (first NE threads) ----
    if (tid < NE) {
        int dd = p.ei[NE + tid];
        int rr = atomicAdd(&p.deg[dd], 1);
        if (rr < MAXDEG) p.esrc[(dd << 6) + rr] = p.ei[tid];
    }

    // ---- msg portion ----
    const int gw = blockIdx.x * 4 + wid;   // 2500 blocks x 4 waves
    const int t0 = gw * TPW;

    const __half* wt = p.we2t + m * 544 + quad * 8;
    f16x8 bfr[17];
    #pragma unroll
    for (int ks = 0; ks < 17; ++ks)
        bfr[ks] = *(const f16x8*)(wt + ks * 32);

    int e0 = t0 * 16;
    int r  = e0 + quad * 4 + (m & 3);
    int s  = p.ei[e0 + m];
    int d  = p.ei[NE + r];
    {
        const float4* s0 = (const float4*)(p.ea + (long)t0 * 512 + lane * 4);
        float4 v0 = s0[0], v1 = s0[64];
        *(float4*)&lds[wid][0][eL * EA_STRIDE + fL]       = v0;
        *(float4*)&lds[wid][0][(8 + eL) * EA_STRIDE + fL] = v1;
    }
    float xf[8];
    {
        const float4* xr = (const float4*)(p.x + s * 16 + xh);
        float4 a0 = xr[0], a1 = xr[1];
        xf[0]=a0.x; xf[1]=a0.y; xf[2]=a0.z; xf[3]=a0.w;
        xf[4]=a1.x; xf[5]=a1.y; xf[6]=a1.z; xf[7]=a1.w;
    }

    int buf = 0;
    #pragma unroll
    for (int it = 0; it < TPW; ++it) {
        const int tile = t0 + it;
        const bool hasnext = it < TPW - 1;

        float4 nv0, nv1;
        int s_n = 0, d_n = 0;
        if (hasnext) {
            const float4* sn = (const float4*)(p.ea + (long)(tile + 1) * 512 + lane * 4);
            nv0 = sn[0]; nv1 = sn[64];
            int e0n = (tile + 1) * 16;
            int rn  = e0n + quad * 4 + (m & 3);
            s_n = p.ei[e0n + m];
            d_n = p.ei[NE + rn];
        }

        float4 ev[4];
        #pragma unroll
        for (int q = 0; q < 4; ++q)
            ev[q] = *(const float4*)&lds[wid][buf][m * EA_STRIDE + pp * 16 + q * 4];

        __half2 xp[4];
        #pragma unroll
        for (int j = 0; j < 4; ++j)
            xp[j] = __float22half2_rn(make_float2(xf[2*j], xf[2*j+1]));

        f32x4 acc = {0.f, 0.f, 0.f, 0.f};
        #pragma unroll
        for (int ks = 0; ks < 16; ++ks) {
            float evv = ((const float*)ev)[ks];
            __half2 eh = __float2half2_rn(evv);
            AFrag a;
            #pragma unroll
            for (int j = 0; j < 4; ++j) a.h2[j] = __hmul2(eh, xp[j]);
            acc = __builtin_amdgcn_mfma_f32_16x16x32_f16(a.v, bfr[ks], acc, 0, 0, 0);
        }
        {
            AFrag a;
            #pragma unroll
            for (int j = 0; j < 4; ++j) a.h2[j] = xp[j];
            acc = __builtin_amdgcn_mfma_f32_16x16x32_f16(a.v, bfr[16], acc, 0, 0, 0);
        }

        if (hasnext) {
            const float4* xr = (const float4*)(p.x + s_n * 16 + xh);
            float4 a0 = xr[0], a1 = xr[1];
            xf[0]=a0.x; xf[1]=a0.y; xf[2]=a0.z; xf[3]=a0.w;
            xf[4]=a1.x; xf[5]=a1.y; xf[6]=a1.z; xf[7]=a1.w;
        }

        // C row = quad*4+rr (edge), col = m (feature); lane (quad<<4)|rr holds dst
        #pragma unroll
        for (int rr = 0; rr < 4; ++rr) {
            int dd = __shfl(d, (quad << 4) | rr);
            atomicAdd(&p.agg[dd * 16 + m], acc[rr]);
        }

        if (hasnext) {
            buf ^= 1;
            *(float4*)&lds[wid][buf][eL * EA_STRIDE + fL]       = nv0;
            *(float4*)&lds[wid][buf][(8 + eL) * EA_STRIDE + fL] = nv1;
            s = s_n; d = d_n;
        }
    }
}

// ---------------- K2: node — h, hp, scores (direct agg read) ----------------
__global__ __launch_bounds__(256) void k_node(Params p) {
    int n = (blockIdx.x * blockDim.x + threadIdx.x) >> 6;
    int lane = threadIdx.x & 63;
    if (n >= NN) return;
    int o = lane & 15;
    float agv = p.agg[n * 16 + o];
    float xv = p.x[n * 16 + o];
    float acc = p.bconv[o] + agv;
    #pragma unroll
    for (int i = 0; i < 16; ++i) acc += __shfl(xv, i) * p.Wroot[i * 16 + o];
    float hv = fmaxf(acc, 0.f);
    float hpacc = 0.f;
    #pragma unroll
    for (int i = 0; i < 16; ++i) hpacc += __shfl(hv, i) * p.Wgat[i * 64 + lane];
    p.hpb[(long)n * 64 + lane] = __float2half(hpacc);
    float ss = hpacc * p.a_src[lane];
    float sd = hpacc * p.a_dst[lane];
    #pragma unroll
    for (int off = 32; off; off >>= 1) {
        ss += __shfl_xor(ss, off);
        sd += __shfl_xor(sd, off);
    }
    if (lane == 0) { p.sc_s[n] = ss; p.sc_d[n] = sd; }
}

// ---------------- K3: GAT + pool + FUSED head (hierarchical last-block-done) --------
// Round-11 lesson: a SINGLE done word = 5000 serialized same-address RMWs at the
// coherence point (~55cy each ~= 115us). Two-level counters spread the traffic:
// 79 chunk counters (64B-strided, <=64 same-address ops each, parallel across L2
// banks) + one global counter touched only 79 times.
__global__ __launch_bounds__(256) void k_gathead(Params p) {
    __shared__ float red[4][64];
    __shared__ int sgid[4];
    __shared__ int lastflag;
    int wid = threadIdx.x >> 6;
    int d = (blockIdx.x * blockDim.x + threadIdx.x) >> 6;   // grid exact: NN/4 blocks
    int lane = threadIdx.x & 63;
    float sdv = p.sc_d[d];
    int gid = p.batch[d];
    float es = p.sc_s[d] + sdv;
    es = (es >= 0.f) ? es : 0.2f * es;
    float l0 = __expf(es);
    float acc = l0 * __half2float(p.hpb[(long)d * 64 + lane]);

    int cnt = p.deg[d]; if (cnt > MAXDEG) cnt = MAXDEG;     // wave-uniform
    bool valid = lane < cnt;
    int s = valid ? p.esrc[(d << 6) + lane] : 0;
    float sc = valid ? p.sc_s[s] + sdv : 0.f;
    sc = (sc >= 0.f) ? sc : 0.2f * sc;
    float pj = valid ? __expf(sc) : 0.f;
    float lsum = pj;

    int k2 = 0;
    for (; k2 + 8 <= cnt; k2 += 8) {       // 8 hpb loads in flight
        int   e0 = __shfl(s, k2),     e1 = __shfl(s, k2 + 1);
        int   e2 = __shfl(s, k2 + 2), e3 = __shfl(s, k2 + 3);
        int   e4 = __shfl(s, k2 + 4), e5 = __shfl(s, k2 + 5);
        int   e6 = __shfl(s, k2 + 6), e7 = __shfl(s, k2 + 7);
        float q0 = __shfl(pj, k2),     q1 = __shfl(pj, k2 + 1);
        float q2 = __shfl(pj, k2 + 2), q3 = __shfl(pj, k2 + 3);
        float q4 = __shfl(pj, k2 + 4), q5 = __shfl(pj, k2 + 5);
        float q6 = __shfl(pj, k2 + 6), q7 = __shfl(pj, k2 + 7);
        float h0 = __half2float(p.hpb[(long)e0 * 64 + lane]);
        float h1 = __half2float(p.hpb[(long)e1 * 64 + lane]);
        float h2 = __half2float(p.hpb[(long)e2 * 64 + lane]);
        float h3 = __half2float(p.hpb[(long)e3 * 64 + lane]);
        float h4 = __half2float(p.hpb[(long)e4 * 64 + lane]);
        float h5 = __half2float(p.hpb[(long)e5 * 64 + lane]);
        float h6 = __half2float(p.hpb[(long)e6 * 64 + lane]);
        float h7 = __half2float(p.hpb[(long)e7 * 64 + lane]);
        acc += q0 * h0 + q1 * h1 + q2 * h2 + q3 * h3
             + q4 * h4 + q5 * h5 + q6 * h6 + q7 * h7;
    }
    for (; k2 + 4 <= cnt; k2 += 4) {
        int   e0 = __shfl(s, k2),     e1 = __shfl(s, k2 + 1);
        int   e2 = __shfl(s, k2 + 2), e3 = __shfl(s, k2 + 3);
        float q0 = __shfl(pj, k2),     q1 = __shfl(pj, k2 + 1);
        float q2 = __shfl(pj, k2 + 2), q3 = __shfl(pj, k2 + 3);
        float h0 = __half2float(p.hpb[(long)e0 * 64 + lane]);
        float h1 = __half2float(p.hpb[(long)e1 * 64 + lane]);
        float h2 = __half2float(p.hpb[(long)e2 * 64 + lane]);
        float h3 = __half2float(p.hpb[(long)e3 * 64 + lane]);
        acc += q0 * h0 + q1 * h1 + q2 * h2 + q3 * h3;
    }
    for (; k2 < cnt; ++k2) {
        int sk = __shfl(s, k2);
        float pk = __shfl(pj, k2);
        acc += pk * __half2float(p.hpb[(long)sk * 64 + lane]);
    }

    #pragma unroll
    for (int off = 32; off; off >>= 1) lsum += __shfl_xor(lsum, off);
    float g = acc / (lsum + l0) + p.bgat[lane];
    g = fmaxf(g, 0.f);

    // block reduce: batch sorted -> block's waves usually share gid
    red[wid][lane] = g;
    if (lane == 0) sgid[wid] = gid;
    __syncthreads();
    bool leader = true;
    #pragma unroll
    for (int w2 = 0; w2 < 3; ++w2)
        if (w2 < wid && sgid[w2] == gid) leader = false;
    if (leader) {
        float tot = g;
        #pragma unroll
        for (int w2 = 1; w2 < 4; ++w2)
            if (w2 > wid && sgid[w2] == gid) tot += red[w2][lane];
        float old = atomicAdd(&p.pooled[gid * 64 + lane], tot);
        // consume the return: forces the RMW ack BEFORE this block's done
        // increments below (program-order s_waitcnt). Per-address contention
        // only ~78-way -> overlapped across blocks, cheap.
        asm volatile("" :: "v"(old));
    }
    __syncthreads();

    // ---- hierarchical last-block-done: chunk counter then global ----
    if (threadIdx.x == 0) {
        int c = blockIdx.x >> 6;
        int csize = min(64, GATBLK - (c << 6));
        int oldc = atomicAdd(&p.dchunk[c * 16], 1);     // 64B-strided counters
        int last = 0;
        if (oldc == csize - 1) {                        // branch consumes ack
            int oldg = atomicAdd(p.done, 1);            // only 79 touches total
            last = (oldg == NCHUNK - 1);
        }
        lastflag = last;
    }
    __syncthreads();
    if (lastflag) {
        // Executed by exactly ONE block, once. Defensive device fence (G16).
        __threadfence();
        // 4 waves x 16 graphs each; pooled read with agent-scope atomic loads
        for (int k = 0; k < 16; ++k) {
            int g2 = wid * 16 + k;
            int r0 = lbound(p.batch, g2);
            int r1 = lbound(p.batch, g2 + 1);
            float inv = 1.f / (float)((r1 - r0) > 0 ? (r1 - r0) : 1);
            float plv = atomic_load_f(&p.pooled[g2 * 64 + lane]) * inv;
            float a0 = p.bfc1[lane], a1 = p.bfc1[64 + lane];
            #pragma unroll 8
            for (int i = 0; i < 64; ++i) {
                float pi = __shfl(plv, i);
                a0 += pi * p.Wfc1[i * 128 + lane];
                a1 += pi * p.Wfc1[i * 128 + 64 + lane];
            }
            a0 = fmaxf(a0, 0.f);
            a1 = fmaxf(a1, 0.f);
            float v = a0 * p.Wfc2[lane] + a1 * p.Wfc2[64 + lane];
            #pragma unroll
            for (int off = 32; off; off >>= 1) v += __shfl_xor(v, off);
            if (lane == 0) p.out[g2] = v + p.bfc2[0];
        }
    }
}

extern "C" void kernel_launch(void* const* d_in, const int* in_sizes, int n_in,
                              void* d_out, int out_size, void* d_ws, size_t ws_size,
                              hipStream_t stream) {
    (void)in_sizes; (void)n_in; (void)out_size; (void)ws_size;
    char* w = (char*)d_ws;
    size_t o_dn  = 0;                               // done    64 B       (k_init)
    size_t o_dc  = 64;                              // dchunk  79*16 int  (k_init)
    size_t o_deg = o_dc + (size_t)NCHUNK * 16 * 4;
    o_deg = (o_deg + 63) & ~(size_t)63;             // deg     NN int     (k_init)
    size_t o_agg = o_deg + (size_t)NN * 4;          // agg     NN*16 f32  (k_init)
    size_t o_pl  = o_agg + (size_t)NN * 16 * 4;     // pooled  NG*64 f32  (k_init)
    size_t o_es  = o_pl  + (size_t)NG * 64 * 4;
    o_es = (o_es + 63) & ~(size_t)63;               // esrc    NN*64 int (5.12MB)
    size_t o_hp  = o_es + (size_t)NN * 64 * 4;      // hpb     NN*64 f16
    size_t o_ss  = o_hp + (size_t)NN * 64 * 2;      // sc_s    NN f32
    size_t o_sd  = o_ss + (size_t)NN * 4;           // sc_d    NN f32
    size_t o_wt  = o_sd + (size_t)NN * 4;           // we2t    16*544 f16 (k_init)
    o_wt = (o_wt + 15) & ~(size_t)15;

    Params P;
    P.x     = (const float*)d_in[0];
    P.ei    = (const int*)d_in[1];
    P.ea    = (const float*)d_in[2];
    P.batch = (const int*)d_in[3];
    P.We    = (const float*)d_in[4];
    P.be    = (const float*)d_in[5];
    P.Wroot = (const float*)d_in[6];
    P.bconv = (const float*)d_in[7];
    P.Wgat  = (const float*)d_in[8];
    P.a_src = (const float*)d_in[9];
    P.a_dst = (const float*)d_in[10];
    P.bgat  = (const float*)d_in[11];
    P.Wfc1  = (const float*)d_in[12];
    P.bfc1  = (const float*)d_in[13];
    P.Wfc2  = (const float*)d_in[14];
    P.bfc2  = (const float*)d_in[15];
    P.out   = (float*)d_out;
    P.done   = (int*)(w + o_dn);
    P.dchunk = (int*)(w + o_dc);
    P.deg    = (int*)(w + o_deg);
    P.agg    = (float*)(w + o_agg);
    P.pooled = (float*)(w + o_pl);
    P.esrc   = (int*)(w + o_es);
    P.hpb    = (__half*)(w + o_hp);
    P.sc_s   = (float*)(w + o_ss);
    P.sc_d   = (float*)(w + o_sd);
    P.we2t   = (__half*)(w + o_wt);

    k_init<<<320, 256, 0, stream>>>(P);            // replaces memset + we2t build
    k_msgprep<<<2500, 256, 0, stream>>>(P);        // prep + msg fused
    k_node<<<(NN + 3) / 4, 256, 0, stream>>>(P);
    k_gathead<<<GATBLK, 256, 0, stream>>>(P);      // gat + pool + head fused
}